// Round 2
// baseline (411.959 us; speedup 1.0000x reference)
//
#include <hip/hip_runtime.h>

// ---------------------------------------------------------------------------
// MLPDeepSet fused fp16-MFMA implementation for gfx950.
//
//  k_prep : convert x->fp16, prepack all weights into MFMA A-fragment order
//           (fp16), init d_out = b_out.
//  k_atoms: AP = x @ W_in[0:256] + b_in ; BP = x @ W_in[256:512]   (f32 out)
//  k_edges: per 256-edge block: h0 = AP[i]+BP[j] (acc init) + rbf/d via one
//           K=32 MFMA step; 6 fused 256x256 layers (fp16 MFMA, f32 acc,
//           SiLU after first 5); per-edge dot with W_out; block-level
//           segment reduce; atomicAdd into d_out.
// ---------------------------------------------------------------------------

typedef _Float16 f16x8 __attribute__((ext_vector_type(8)));
typedef __fp16   fp16v2 __attribute__((ext_vector_type(2)));
typedef float    f32x4 __attribute__((ext_vector_type(4)));
typedef unsigned int u32x4 __attribute__((ext_vector_type(4)));
typedef unsigned int u32x2 __attribute__((ext_vector_type(2)));

union H8 { f16x8 v; _Float16 h[8]; u32x4 u; };
union H2 { fp16v2 h; unsigned int u; };

#define MFMA16(a, b, c) __builtin_amdgcn_mfma_f32_16x16x32_f16((a), (b), (c), 0, 0, 0)

// workspace byte offsets
#define WS_WP   0u          // 6 layers  : 6*65536 halves = 786432 B
#define WS_WPI  786432u     // 65536 halves = 131072 B
#define WS_WPJ  917504u     // 65536 halves = 131072 B
#define WS_WPR  1048576u    // 8192 halves  = 16384 B   (rbf+d, K padded to 32)
#define WS_XH   1064960u    // 2097152 halves = 4194304 B
#define WS_AP   5259264u    // 2097152 f32 = 8388608 B
#define WS_BP   13647872u   // 2097152 f32 = 8388608 B
// total 22036480 B

// ---------------------------------------------------------------------------
__global__ __launch_bounds__(256) void k_prep(
    const float* __restrict__ x, const float* __restrict__ W_in,
    const float* __restrict__ Ws, const float* __restrict__ b_out,
    _Float16* __restrict__ wp, _Float16* __restrict__ wpi,
    _Float16* __restrict__ wpj, _Float16* __restrict__ wpr,
    _Float16* __restrict__ xh, float* __restrict__ out)
{
  int i = blockIdx.x * 256 + threadIdx.x;
  if (i < 2097152) { xh[i] = (_Float16)x[i]; return; }
  i -= 2097152;
  if (i < 393216) {  // 6 hidden layers, A-fragment order (A = W^T)
    int m = i >> 16, r = i & 65535;
    int j = r & 7, lane = (r >> 3) & 63, ks = (r >> 9) & 7, nt = (r >> 12) & 15;
    int k = ks * 32 + (lane >> 4) * 8 + j, n = nt * 16 + (lane & 15);
    wp[i] = (_Float16)Ws[(m * 256 + k) * 256 + n];
    return;
  }
  i -= 393216;
  if (i < 65536) {   // W_in rows 0..255 (x_i part)
    int j = i & 7, lane = (i >> 3) & 63, ks = (i >> 9) & 7, nt = (i >> 12) & 15;
    int k = ks * 32 + (lane >> 4) * 8 + j, n = nt * 16 + (lane & 15);
    wpi[i] = (_Float16)W_in[k * 256 + n];
    return;
  }
  i -= 65536;
  if (i < 65536) {   // W_in rows 256..511 (x_j part)
    int j = i & 7, lane = (i >> 3) & 63, ks = (i >> 9) & 7, nt = (i >> 12) & 15;
    int k = ks * 32 + (lane >> 4) * 8 + j, n = nt * 16 + (lane & 15);
    wpj[i] = (_Float16)W_in[(256 + k) * 256 + n];
    return;
  }
  i -= 65536;
  if (i < 8192) {    // rbf rows 512..531 + d row 532, K padded 20+1 -> 32
    int j = i & 7, lane = (i >> 3) & 63, nt = (i >> 9) & 15;
    int k = (lane >> 4) * 8 + j, n = nt * 16 + (lane & 15);
    float v = 0.0f;
    if (k < 20)       v = W_in[(512 + k) * 256 + n];
    else if (k == 20) v = W_in[532 * 256 + n];
    wpr[i] = (_Float16)v;
    return;
  }
  i -= 8192;
  if (i < 8192) out[i] = b_out[0];
}

// ---------------------------------------------------------------------------
// AP/BP: M=8192 atoms, K=256, N=256. BM=64 atoms/block, 4 waves (one 64-n
// slice each). blockIdx.y selects AP (with b_in) or BP.
__global__ __launch_bounds__(256) void k_atoms(
    const _Float16* __restrict__ xh,
    const _Float16* __restrict__ wpi, const _Float16* __restrict__ wpj,
    const float* __restrict__ b_in,
    float* __restrict__ AP, float* __restrict__ BP)
{
  const int tid = threadIdx.x;
  const int l = tid & 63, w = tid >> 6;
  const int g = l >> 4, c = l & 15;
  const int which = blockIdx.y;
  const _Float16* wpx = which ? wpj : wpi;
  float* outp = which ? BP : AP;
  const int abase = blockIdx.x * 64;

  f32x4 acc[4][4];
#pragma unroll
  for (int nf = 0; nf < 4; ++nf)
#pragma unroll
    for (int at = 0; at < 4; ++at) acc[nf][at] = (f32x4)0.0f;

#pragma unroll
  for (int ks = 0; ks < 8; ++ks) {
    f16x8 a[4];
#pragma unroll
    for (int nf = 0; nf < 4; ++nf) {
      H8 t; t.u = *(const u32x4*)(wpx + (((w * 4 + nf) * 8 + ks) * 64 + l) * 8);
      a[nf] = t.v;
    }
#pragma unroll
    for (int at = 0; at < 4; ++at) {
      H8 b; b.u = *(const u32x4*)(xh + (abase + at * 16 + c) * 256 + ks * 32 + g * 8);
#pragma unroll
      for (int nf = 0; nf < 4; ++nf)
        acc[nf][at] = MFMA16(a[nf], b.v, acc[nf][at]);
    }
  }

#pragma unroll
  for (int nf = 0; nf < 4; ++nf) {
    const int n = w * 64 + nf * 16 + g * 4;
    f32x4 bias = (f32x4)0.0f;
    if (!which) bias = *(const f32x4*)(b_in + n);
#pragma unroll
    for (int at = 0; at < 4; ++at) {
      const int atom = abase + at * 16 + c;
      *(f32x4*)(outp + atom * 256 + n) = acc[nf][at] + bias;
    }
  }
}

// ---------------------------------------------------------------------------
// Fused edge pipeline. 256 edges/block, 512 threads = 8 waves laid out as
// 2 edge-groups(128) x 4 n-groups(64). h tile [256 edges][256 feat] fp16 in
// LDS, XOR-swizzled (byte ^= (edge&7)<<4) for bank-even ds_read_b128.
__global__ __launch_bounds__(512, 2) void k_edges(
    const float* __restrict__ AP, const float* __restrict__ BP,
    const int* __restrict__ idx_i, const int* __restrict__ idx_j,
    const float* __restrict__ d_ij,
    const _Float16* __restrict__ wp, const _Float16* __restrict__ wpr,
    const float* __restrict__ bs, const float* __restrict__ W_out,
    float* __restrict__ out)
{
  __shared__ __align__(16) char hb[131072];
  __shared__ float d_lds[256];
  __shared__ int   ii_lds[256];
  __shared__ int   jj_lds[256];
  __shared__ float oacc[256];

  const int tid = threadIdx.x;
  const int l = tid & 63, w = tid >> 6;
  const int ge = w >> 2, gn = w & 3;
  const int g = l >> 4, c = l & 15;
  const int ebase = blockIdx.x * 256;
  const int we = ge * 128;        // wave's local edge base
  const int nb = gn * 64;         // wave's feature base
  const int sw = (l & 7) << 4;    // swizzle field (edge&7 == l&7 for our tiles)

  if (tid < 256) {
    ii_lds[tid] = idx_i[ebase + tid];
    jj_lds[tid] = idx_j[ebase + tid];
    d_lds[tid]  = d_ij[ebase + tid];
    oacc[tid]   = 0.0f;
  }
  __syncthreads();

  f32x4 acc[4][8];  // [nf][et] : D = h^T tile (features x edges)

  // ---- input layer: acc = AP[idx_i] + BP[idx_j] (D-layout gather) ----
#pragma unroll
  for (int et = 0; et < 8; ++et) {
    const int el = we + et * 16 + c;
    const float* ra = AP + ii_lds[el] * 256;
    const float* rb = BP + jj_lds[el] * 256;
#pragma unroll
    for (int nf = 0; nf < 4; ++nf) {
      const int n = nb + nf * 16 + g * 4;
      acc[nf][et] = *(const f32x4*)(ra + n) + *(const f32x4*)(rb + n);
    }
  }
  // rbf(20) + d contribution: single K=32 MFMA step, B built in-register
  {
    const float STEP = 15.0f / 19.0f;
    const float COEF = -0.5f / (STEP * STEP);
    f16x8 afr[4];
#pragma unroll
    for (int nf = 0; nf < 4; ++nf) {
      H8 t; t.u = *(const u32x4*)(wpr + ((gn * 4 + nf) * 64 + l) * 8);
      afr[nf] = t.v;
    }
#pragma unroll
    for (int et = 0; et < 8; ++et) {
      const int el = we + et * 16 + c;
      const float d = d_lds[el];
      H8 bb;
#pragma unroll
      for (int j = 0; j < 8; ++j) {
        const int k = g * 8 + j;
        float v = 0.0f;
        if (k < 20)       { const float df = d - (float)k * STEP; v = __expf(COEF * df * df); }
        else if (k == 20) { v = d; }
        bb.h[j] = (_Float16)v;
      }
#pragma unroll
      for (int nf = 0; nf < 4; ++nf)
        acc[nf][et] = MFMA16(afr[nf], bb.v, acc[nf][et]);
    }
  }
  // write h0 to LDS (no bias [in AP], no activation)
#pragma unroll
  for (int nf = 0; nf < 4; ++nf) {
    const int obase = (nb + nf * 16 + g * 4) * 2;
#pragma unroll
    for (int et = 0; et < 8; ++et) {
      const int el = we + et * 16 + c;
      H2 lo, hi;
      lo.h = __builtin_amdgcn_cvt_pkrtz(acc[nf][et][0], acc[nf][et][1]);
      hi.h = __builtin_amdgcn_cvt_pkrtz(acc[nf][et][2], acc[nf][et][3]);
      u32x2 q; q[0] = lo.u; q[1] = hi.u;
      *(u32x2*)(hb + el * 512 + (obase ^ sw)) = q;
    }
  }
  __syncthreads();

  // one fused hidden-layer matmul: acc = (h_lds @ W)^T, W from prepacked A-frags
  auto mfma_layer = [&](const _Float16* wl) {
#pragma unroll
    for (int nf = 0; nf < 4; ++nf)
#pragma unroll
      for (int et = 0; et < 8; ++et) acc[nf][et] = (f32x4)0.0f;
#pragma unroll
    for (int ks = 0; ks < 8; ++ks) {
      f16x8 a[4];
#pragma unroll
      for (int nf = 0; nf < 4; ++nf) {
        H8 t; t.u = *(const u32x4*)(wl + (((gn * 4 + nf) * 8 + ks) * 64 + l) * 8);
        a[nf] = t.v;
      }
      const int o = (ks * 64 + g * 16) ^ sw;
#pragma unroll
      for (int et = 0; et < 8; ++et) {
        const int el = we + et * 16 + c;
        H8 b; b.u = *(const u32x4*)(hb + el * 512 + o);
#pragma unroll
        for (int nf = 0; nf < 4; ++nf)
          acc[nf][et] = MFMA16(a[nf], b.v, acc[nf][et]);
      }
    }
  };

#pragma unroll 1
  for (int ly = 0; ly < 5; ++ly) {
    mfma_layer(wp + ly * 65536);
    __syncthreads();  // all waves done reading h before in-place overwrite
#pragma unroll
    for (int nf = 0; nf < 4; ++nf) {
      const int n = nb + nf * 16 + g * 4;
      const f32x4 bias = *(const f32x4*)(bs + ly * 256 + n);
      const int obase = n * 2;
#pragma unroll
      for (int et = 0; et < 8; ++et) {
        f32x4 v = acc[nf][et] + bias;
#pragma unroll
        for (int j = 0; j < 4; ++j)
          v[j] = v[j] / (1.0f + __expf(-v[j]));   // SiLU
        const int el = we + et * 16 + c;
        H2 lo, hi;
        lo.h = __builtin_amdgcn_cvt_pkrtz(v[0], v[1]);
        hi.h = __builtin_amdgcn_cvt_pkrtz(v[2], v[3]);
        u32x2 q; q[0] = lo.u; q[1] = hi.u;
        *(u32x2*)(hb + el * 512 + (obase ^ sw)) = q;
      }
    }
    __syncthreads();
  }

  // layer 6 (no activation): keep in registers, fold W_out dot immediately
  mfma_layer(wp + 5 * 65536);
  float sum[8];
#pragma unroll
  for (int et = 0; et < 8; ++et) sum[et] = 0.0f;
#pragma unroll
  for (int nf = 0; nf < 4; ++nf) {
    const int n = nb + nf * 16 + g * 4;
    const f32x4 bias = *(const f32x4*)(bs + 5 * 256 + n);
    const f32x4 wo   = *(const f32x4*)(W_out + n);
#pragma unroll
    for (int et = 0; et < 8; ++et) {
      const f32x4 v = acc[nf][et] + bias;
      sum[et] += v[0] * wo[0] + v[1] * wo[1] + v[2] * wo[2] + v[3] * wo[3];
    }
  }
#pragma unroll
  for (int et = 0; et < 8; ++et) {
    float s = sum[et];
    s += __shfl_xor(s, 16, 64);
    s += __shfl_xor(s, 32, 64);
    if (l < 16) atomicAdd(&oacc[we + et * 16 + l], s);
  }
  __syncthreads();
  if (tid < 256) atomicAdd(out + ii_lds[tid], oacc[tid]);
}

// ---------------------------------------------------------------------------
extern "C" void kernel_launch(void* const* d_in, const int* in_sizes, int n_in,
                              void* d_out, int out_size, void* d_ws, size_t ws_size,
                              hipStream_t stream) {
  (void)in_sizes; (void)n_in; (void)out_size; (void)ws_size;
  const float* x     = (const float*)d_in[0];
  const float* d_ij  = (const float*)d_in[1];
  const int*   idx_i = (const int*)d_in[2];
  const int*   idx_j = (const int*)d_in[3];
  const float* W_in  = (const float*)d_in[4];
  const float* b_in  = (const float*)d_in[5];
  const float* Ws    = (const float*)d_in[6];
  const float* bs    = (const float*)d_in[7];
  const float* W_out = (const float*)d_in[8];
  const float* b_out = (const float*)d_in[9];
  float* out = (float*)d_out;
  char* ws = (char*)d_ws;

  _Float16* wp  = (_Float16*)(ws + WS_WP);
  _Float16* wpi = (_Float16*)(ws + WS_WPI);
  _Float16* wpj = (_Float16*)(ws + WS_WPJ);
  _Float16* wpr = (_Float16*)(ws + WS_WPR);
  _Float16* xh  = (_Float16*)(ws + WS_XH);
  float* AP = (float*)(ws + WS_AP);
  float* BP = (float*)(ws + WS_BP);

  // prep: 2097152 + 393216 + 65536 + 65536 + 8192 + 8192 = 2637888 items
  hipLaunchKernelGGL(k_prep, dim3(10305), dim3(256), 0, stream,
                     x, W_in, Ws, b_out, wp, wpi, wpj, wpr, xh, out);
  hipLaunchKernelGGL(k_atoms, dim3(128, 2), dim3(256), 0, stream,
                     xh, wpi, wpj, b_in, AP, BP);
  hipLaunchKernelGGL(k_edges, dim3(1024), dim3(512), 0, stream,
                     AP, BP, idx_i, idx_j, d_ij, wp, wpr, bs, W_out, out);
}

// Round 3
// 400.264 us; speedup vs baseline: 1.0292x; 1.0292x over previous
//
#include <hip/hip_runtime.h>

// ---------------------------------------------------------------------------
// MLPDeepSet fused fp16-MFMA implementation for gfx950.
//
//  k_prep : convert x->fp16, prepack all weights into MFMA A-fragment order
//           (fp16), init d_out = b_out.
//  k_atoms: AP = x @ W_in[0:256] + b_in ; BP = x @ W_in[256:512]   (f32 out)
//  k_edges: per 128-edge block (2 blocks/CU): h0 = AP[i]+BP[j] + rbf/d via one
//           K=32 MFMA step; 6 fused 256x256 layers (fp16 MFMA, f32 acc,
//           SiLU after first 5); per-edge dot with W_out; block-level
//           segment reduce; atomicAdd into d_out.
//  R3 changes: 128-edge blocks (LDS 66KB -> 2 blocks/CU), acc[4][4] (64 AGPR),
//  launch_bounds(512,4) for 4 waves/SIMD; 5-bit row swizzle
//  sw=(c<<4)|((c&1)<<8) -> 2-way (free) LDS access instead of 8-way.
// ---------------------------------------------------------------------------

typedef _Float16 f16x8 __attribute__((ext_vector_type(8)));
typedef __fp16   fp16v2 __attribute__((ext_vector_type(2)));
typedef float    f32x4 __attribute__((ext_vector_type(4)));
typedef unsigned int u32x4 __attribute__((ext_vector_type(4)));
typedef unsigned int u32x2 __attribute__((ext_vector_type(2)));

union H8 { f16x8 v; _Float16 h[8]; u32x4 u; };
union H2 { fp16v2 h; unsigned int u; };

#define MFMA16(a, b, c) __builtin_amdgcn_mfma_f32_16x16x32_f16((a), (b), (c), 0, 0, 0)

// workspace byte offsets
#define WS_WP   0u          // 6 layers  : 6*65536 halves = 786432 B
#define WS_WPI  786432u     // 65536 halves = 131072 B
#define WS_WPJ  917504u     // 65536 halves = 131072 B
#define WS_WPR  1048576u    // 8192 halves  = 16384 B   (rbf+d, K padded to 32)
#define WS_XH   1064960u    // 2097152 halves = 4194304 B
#define WS_AP   5259264u    // 2097152 f32 = 8388608 B
#define WS_BP   13647872u   // 2097152 f32 = 8388608 B
// total 22036480 B

// ---------------------------------------------------------------------------
__global__ __launch_bounds__(256) void k_prep(
    const float* __restrict__ x, const float* __restrict__ W_in,
    const float* __restrict__ Ws, const float* __restrict__ b_out,
    _Float16* __restrict__ wp, _Float16* __restrict__ wpi,
    _Float16* __restrict__ wpj, _Float16* __restrict__ wpr,
    _Float16* __restrict__ xh, float* __restrict__ out)
{
  int i = blockIdx.x * 256 + threadIdx.x;
  if (i < 2097152) { xh[i] = (_Float16)x[i]; return; }
  i -= 2097152;
  if (i < 393216) {  // 6 hidden layers, A-fragment order (A = W^T)
    int m = i >> 16, r = i & 65535;
    int j = r & 7, lane = (r >> 3) & 63, ks = (r >> 9) & 7, nt = (r >> 12) & 15;
    int k = ks * 32 + (lane >> 4) * 8 + j, n = nt * 16 + (lane & 15);
    wp[i] = (_Float16)Ws[(m * 256 + k) * 256 + n];
    return;
  }
  i -= 393216;
  if (i < 65536) {   // W_in rows 0..255 (x_i part)
    int j = i & 7, lane = (i >> 3) & 63, ks = (i >> 9) & 7, nt = (i >> 12) & 15;
    int k = ks * 32 + (lane >> 4) * 8 + j, n = nt * 16 + (lane & 15);
    wpi[i] = (_Float16)W_in[k * 256 + n];
    return;
  }
  i -= 65536;
  if (i < 65536) {   // W_in rows 256..511 (x_j part)
    int j = i & 7, lane = (i >> 3) & 63, ks = (i >> 9) & 7, nt = (i >> 12) & 15;
    int k = ks * 32 + (lane >> 4) * 8 + j, n = nt * 16 + (lane & 15);
    wpj[i] = (_Float16)W_in[(256 + k) * 256 + n];
    return;
  }
  i -= 65536;
  if (i < 8192) {    // rbf rows 512..531 + d row 532, K padded 20+1 -> 32
    int j = i & 7, lane = (i >> 3) & 63, nt = (i >> 9) & 15;
    int k = (lane >> 4) * 8 + j, n = nt * 16 + (lane & 15);
    float v = 0.0f;
    if (k < 20)       v = W_in[(512 + k) * 256 + n];
    else if (k == 20) v = W_in[532 * 256 + n];
    wpr[i] = (_Float16)v;
    return;
  }
  i -= 8192;
  if (i < 8192) out[i] = b_out[0];
}

// ---------------------------------------------------------------------------
// AP/BP: M=8192 atoms, K=256, N=256. BM=64 atoms/block, 4 waves (one 64-n
// slice each). blockIdx.y selects AP (with b_in) or BP.
__global__ __launch_bounds__(256) void k_atoms(
    const _Float16* __restrict__ xh,
    const _Float16* __restrict__ wpi, const _Float16* __restrict__ wpj,
    const float* __restrict__ b_in,
    float* __restrict__ AP, float* __restrict__ BP)
{
  const int tid = threadIdx.x;
  const int l = tid & 63, w = tid >> 6;
  const int g = l >> 4, c = l & 15;
  const int which = blockIdx.y;
  const _Float16* wpx = which ? wpj : wpi;
  float* outp = which ? BP : AP;
  const int abase = blockIdx.x * 64;

  f32x4 acc[4][4];
#pragma unroll
  for (int nf = 0; nf < 4; ++nf)
#pragma unroll
    for (int at = 0; at < 4; ++at) acc[nf][at] = (f32x4)0.0f;

#pragma unroll
  for (int ks = 0; ks < 8; ++ks) {
    f16x8 a[4];
#pragma unroll
    for (int nf = 0; nf < 4; ++nf) {
      H8 t; t.u = *(const u32x4*)(wpx + (((w * 4 + nf) * 8 + ks) * 64 + l) * 8);
      a[nf] = t.v;
    }
#pragma unroll
    for (int at = 0; at < 4; ++at) {
      H8 b; b.u = *(const u32x4*)(xh + (abase + at * 16 + c) * 256 + ks * 32 + g * 8);
#pragma unroll
      for (int nf = 0; nf < 4; ++nf)
        acc[nf][at] = MFMA16(a[nf], b.v, acc[nf][at]);
    }
  }

#pragma unroll
  for (int nf = 0; nf < 4; ++nf) {
    const int n = w * 64 + nf * 16 + g * 4;
    f32x4 bias = (f32x4)0.0f;
    if (!which) bias = *(const f32x4*)(b_in + n);
#pragma unroll
    for (int at = 0; at < 4; ++at) {
      const int atom = abase + at * 16 + c;
      *(f32x4*)(outp + atom * 256 + n) = acc[nf][at] + bias;
    }
  }
}

// ---------------------------------------------------------------------------
// Fused edge pipeline. 128 edges/block, 512 threads = 8 waves laid out as
// 2 edge-groups(64) x 4 n-groups(64). h tile [128 edges][256 feat] fp16 in
// LDS. Row swizzle: addr = el*512 + (o ^ sw), sw = (c<<4)|((c&1)<<8) ->
// b128 reads land 2 lanes/slot (free), b64 writes conflict-free.
__global__ __launch_bounds__(512, 4) void k_edges(
    const float* __restrict__ AP, const float* __restrict__ BP,
    const int* __restrict__ idx_i, const int* __restrict__ idx_j,
    const float* __restrict__ d_ij,
    const _Float16* __restrict__ wp, const _Float16* __restrict__ wpr,
    const float* __restrict__ bs, const float* __restrict__ W_out,
    float* __restrict__ out)
{
  __shared__ __align__(16) char hb[65536];
  __shared__ float d_lds[128];
  __shared__ int   ii_lds[128];
  __shared__ int   jj_lds[128];
  __shared__ float oacc[128];

  const int tid = threadIdx.x;
  const int l = tid & 63, w = tid >> 6;
  const int ge = w >> 2, gn = w & 3;
  const int g = l >> 4, c = l & 15;
  const int ebase = blockIdx.x * 128;
  const int we = ge * 64;         // wave's local edge base
  const int nb = gn * 64;         // wave's feature base
  const int sw = (c << 4) | ((c & 1) << 8);  // 5-bit row swizzle

  if (tid < 128) {
    ii_lds[tid] = idx_i[ebase + tid];
    jj_lds[tid] = idx_j[ebase + tid];
    d_lds[tid]  = d_ij[ebase + tid];
    oacc[tid]   = 0.0f;
  }
  __syncthreads();

  f32x4 acc[4][4];  // [nf][et] : D = h^T tile (features x edges)

  // ---- input layer: acc = AP[idx_i] + BP[idx_j] (D-layout gather) ----
#pragma unroll
  for (int et = 0; et < 4; ++et) {
    const int el = we + et * 16 + c;
    const float* ra = AP + ii_lds[el] * 256;
    const float* rb = BP + jj_lds[el] * 256;
#pragma unroll
    for (int nf = 0; nf < 4; ++nf) {
      const int n = nb + nf * 16 + g * 4;
      acc[nf][et] = *(const f32x4*)(ra + n) + *(const f32x4*)(rb + n);
    }
  }
  // rbf(20) + d contribution: single K=32 MFMA step, B built in-register
  {
    const float STEP = 15.0f / 19.0f;
    const float COEF = -0.5f / (STEP * STEP);
    f16x8 afr[4];
#pragma unroll
    for (int nf = 0; nf < 4; ++nf) {
      H8 t; t.u = *(const u32x4*)(wpr + ((gn * 4 + nf) * 64 + l) * 8);
      afr[nf] = t.v;
    }
#pragma unroll
    for (int et = 0; et < 4; ++et) {
      const int el = we + et * 16 + c;
      const float d = d_lds[el];
      H8 bb;
#pragma unroll
      for (int j = 0; j < 8; ++j) {
        const int k = g * 8 + j;
        float v = 0.0f;
        if (k < 20)       { const float df = d - (float)k * STEP; v = __expf(COEF * df * df); }
        else if (k == 20) { v = d; }
        bb.h[j] = (_Float16)v;
      }
#pragma unroll
      for (int nf = 0; nf < 4; ++nf)
        acc[nf][et] = MFMA16(afr[nf], bb.v, acc[nf][et]);
    }
  }
  // write h0 to LDS (no bias [in AP], no activation)
#pragma unroll
  for (int nf = 0; nf < 4; ++nf) {
    const int obase = (nb + nf * 16 + g * 4) * 2;
#pragma unroll
    for (int et = 0; et < 4; ++et) {
      const int el = we + et * 16 + c;
      H2 lo, hi;
      lo.h = __builtin_amdgcn_cvt_pkrtz(acc[nf][et][0], acc[nf][et][1]);
      hi.h = __builtin_amdgcn_cvt_pkrtz(acc[nf][et][2], acc[nf][et][3]);
      u32x2 q; q[0] = lo.u; q[1] = hi.u;
      *(u32x2*)(hb + el * 512 + (obase ^ sw)) = q;
    }
  }
  __syncthreads();

  // one fused hidden-layer matmul: acc = (h_lds @ W)^T, W from prepacked A-frags
  auto mfma_layer = [&](const _Float16* wl) {
#pragma unroll
    for (int nf = 0; nf < 4; ++nf)
#pragma unroll
      for (int et = 0; et < 4; ++et) acc[nf][et] = (f32x4)0.0f;
#pragma unroll
    for (int ks = 0; ks < 8; ++ks) {
      f16x8 a[4];
#pragma unroll
      for (int nf = 0; nf < 4; ++nf) {
        H8 t; t.u = *(const u32x4*)(wl + (((gn * 4 + nf) * 8 + ks) * 64 + l) * 8);
        a[nf] = t.v;
      }
      const int o = (ks * 64 + g * 16) ^ sw;
#pragma unroll
      for (int et = 0; et < 4; ++et) {
        const int el = we + et * 16 + c;
        H8 b; b.u = *(const u32x4*)(hb + el * 512 + o);
#pragma unroll
        for (int nf = 0; nf < 4; ++nf)
          acc[nf][et] = MFMA16(a[nf], b.v, acc[nf][et]);
      }
    }
  };

#pragma unroll 1
  for (int ly = 0; ly < 5; ++ly) {
    mfma_layer(wp + ly * 65536);
    __syncthreads();  // all waves done reading h before in-place overwrite
#pragma unroll
    for (int nf = 0; nf < 4; ++nf) {
      const int n = nb + nf * 16 + g * 4;
      const f32x4 bias = *(const f32x4*)(bs + ly * 256 + n);
      const int obase = n * 2;
#pragma unroll
      for (int et = 0; et < 4; ++et) {
        f32x4 v = acc[nf][et] + bias;
#pragma unroll
        for (int j = 0; j < 4; ++j)
          v[j] = v[j] / (1.0f + __expf(-v[j]));   // SiLU
        const int el = we + et * 16 + c;
        H2 lo, hi;
        lo.h = __builtin_amdgcn_cvt_pkrtz(v[0], v[1]);
        hi.h = __builtin_amdgcn_cvt_pkrtz(v[2], v[3]);
        u32x2 q; q[0] = lo.u; q[1] = hi.u;
        *(u32x2*)(hb + el * 512 + (obase ^ sw)) = q;
      }
    }
    __syncthreads();
  }

  // layer 6 (no activation): keep in registers, fold W_out dot immediately
  mfma_layer(wp + 5 * 65536);
  float sum[4];
#pragma unroll
  for (int et = 0; et < 4; ++et) sum[et] = 0.0f;
#pragma unroll
  for (int nf = 0; nf < 4; ++nf) {
    const int n = nb + nf * 16 + g * 4;
    const f32x4 bias = *(const f32x4*)(bs + 5 * 256 + n);
    const f32x4 wo   = *(const f32x4*)(W_out + n);
#pragma unroll
    for (int et = 0; et < 4; ++et) {
      const f32x4 v = acc[nf][et] + bias;
      sum[et] += v[0] * wo[0] + v[1] * wo[1] + v[2] * wo[2] + v[3] * wo[3];
    }
  }
#pragma unroll
  for (int et = 0; et < 4; ++et) {
    float s = sum[et];
    s += __shfl_xor(s, 16, 64);
    s += __shfl_xor(s, 32, 64);
    if (l < 16) atomicAdd(&oacc[we + et * 16 + l], s);
  }
  __syncthreads();
  if (tid < 128) atomicAdd(out + ii_lds[tid], oacc[tid]);
}

// ---------------------------------------------------------------------------
extern "C" void kernel_launch(void* const* d_in, const int* in_sizes, int n_in,
                              void* d_out, int out_size, void* d_ws, size_t ws_size,
                              hipStream_t stream) {
  (void)in_sizes; (void)n_in; (void)out_size; (void)ws_size;
  const float* x     = (const float*)d_in[0];
  const float* d_ij  = (const float*)d_in[1];
  const int*   idx_i = (const int*)d_in[2];
  const int*   idx_j = (const int*)d_in[3];
  const float* W_in  = (const float*)d_in[4];
  const float* b_in  = (const float*)d_in[5];
  const float* Ws    = (const float*)d_in[6];
  const float* bs    = (const float*)d_in[7];
  const float* W_out = (const float*)d_in[8];
  const float* b_out = (const float*)d_in[9];
  float* out = (float*)d_out;
  char* ws = (char*)d_ws;

  _Float16* wp  = (_Float16*)(ws + WS_WP);
  _Float16* wpi = (_Float16*)(ws + WS_WPI);
  _Float16* wpj = (_Float16*)(ws + WS_WPJ);
  _Float16* wpr = (_Float16*)(ws + WS_WPR);
  _Float16* xh  = (_Float16*)(ws + WS_XH);
  float* AP = (float*)(ws + WS_AP);
  float* BP = (float*)(ws + WS_BP);

  // prep: 2097152 + 393216 + 65536 + 65536 + 8192 + 8192 = 2637888 items
  hipLaunchKernelGGL(k_prep, dim3(10305), dim3(256), 0, stream,
                     x, W_in, Ws, b_out, wp, wpi, wpj, wpr, xh, out);
  hipLaunchKernelGGL(k_atoms, dim3(128, 2), dim3(256), 0, stream,
                     xh, wpi, wpj, b_in, AP, BP);
  hipLaunchKernelGGL(k_edges, dim3(2048), dim3(512), 0, stream,
                     AP, BP, idx_i, idx_j, d_ij, wp, wpr, bs, W_out, out);
}

// Round 4
// 281.617 us; speedup vs baseline: 1.4628x; 1.4213x over previous
//
#include <hip/hip_runtime.h>

// ---------------------------------------------------------------------------
// MLPDeepSet fused fp16-MFMA implementation for gfx950.
//
//  k_prep : convert x->fp16, prepack all weights into MFMA A-fragment order
//           (fp16), init d_out = b_out.
//  k_atoms: AP = x @ W_in[0:256] + b_in ; BP = x @ W_in[256:512]  (fp16 out)
//  k_edges: per 128-edge block (2 blocks/CU): h0 = rbf/d MFMA + AP[i]+BP[j]
//           (pk_add fp16); 6 fused 256x256 layers (fp16 MFMA, f32 acc,
//           fast SiLU after first 5); per-edge dot with W_out; block-level
//           segment reduce; atomicAdd into d_out.
//  R4: fast SiLU (exp2+rcp, 5 ops/val), bias-seeded acc, fp16 AP/BP gathers
//      (half traffic), s_setprio around MFMA loop.
// ---------------------------------------------------------------------------

typedef _Float16 f16x8 __attribute__((ext_vector_type(8)));
typedef _Float16 f16x4 __attribute__((ext_vector_type(4)));
typedef __fp16   fp16v2 __attribute__((ext_vector_type(2)));
typedef float    f32x4 __attribute__((ext_vector_type(4)));
typedef unsigned int u32x4 __attribute__((ext_vector_type(4)));
typedef unsigned int u32x2 __attribute__((ext_vector_type(2)));

union H8 { f16x8 v; _Float16 h[8]; u32x4 u; };
union H4 { f16x4 v; u32x2 u; };
union H2 { fp16v2 h; unsigned int u; };

#define MFMA16(a, b, c) __builtin_amdgcn_mfma_f32_16x16x32_f16((a), (b), (c), 0, 0, 0)

#define LOG2E 1.44269504088896340736f

// workspace byte offsets
#define WS_WP   0u          // 6 layers  : 6*65536 halves = 786432 B
#define WS_WPI  786432u     // 65536 halves = 131072 B
#define WS_WPJ  917504u     // 65536 halves = 131072 B
#define WS_WPR  1048576u    // 8192 halves  = 16384 B   (rbf+d, K padded to 32)
#define WS_XH   1064960u    // 2097152 halves = 4194304 B
#define WS_AP   5259264u    // 2097152 fp16 = 4194304 B
#define WS_BP   9453568u    // 2097152 fp16 = 4194304 B
// total 13647872 B

// ---------------------------------------------------------------------------
__global__ __launch_bounds__(256) void k_prep(
    const float* __restrict__ x, const float* __restrict__ W_in,
    const float* __restrict__ Ws, const float* __restrict__ b_out,
    _Float16* __restrict__ wp, _Float16* __restrict__ wpi,
    _Float16* __restrict__ wpj, _Float16* __restrict__ wpr,
    _Float16* __restrict__ xh, float* __restrict__ out)
{
  int i = blockIdx.x * 256 + threadIdx.x;
  if (i < 2097152) { xh[i] = (_Float16)x[i]; return; }
  i -= 2097152;
  if (i < 393216) {  // 6 hidden layers, A-fragment order (A = W^T)
    int m = i >> 16, r = i & 65535;
    int j = r & 7, lane = (r >> 3) & 63, ks = (r >> 9) & 7, nt = (r >> 12) & 15;
    int k = ks * 32 + (lane >> 4) * 8 + j, n = nt * 16 + (lane & 15);
    wp[i] = (_Float16)Ws[(m * 256 + k) * 256 + n];
    return;
  }
  i -= 393216;
  if (i < 65536) {   // W_in rows 0..255 (x_i part)
    int j = i & 7, lane = (i >> 3) & 63, ks = (i >> 9) & 7, nt = (i >> 12) & 15;
    int k = ks * 32 + (lane >> 4) * 8 + j, n = nt * 16 + (lane & 15);
    wpi[i] = (_Float16)W_in[k * 256 + n];
    return;
  }
  i -= 65536;
  if (i < 65536) {   // W_in rows 256..511 (x_j part)
    int j = i & 7, lane = (i >> 3) & 63, ks = (i >> 9) & 7, nt = (i >> 12) & 15;
    int k = ks * 32 + (lane >> 4) * 8 + j, n = nt * 16 + (lane & 15);
    wpj[i] = (_Float16)W_in[(256 + k) * 256 + n];
    return;
  }
  i -= 65536;
  if (i < 8192) {    // rbf rows 512..531 + d row 532, K padded 20+1 -> 32
    int j = i & 7, lane = (i >> 3) & 63, nt = (i >> 9) & 15;
    int k = (lane >> 4) * 8 + j, n = nt * 16 + (lane & 15);
    float v = 0.0f;
    if (k < 20)       v = W_in[(512 + k) * 256 + n];
    else if (k == 20) v = W_in[532 * 256 + n];
    wpr[i] = (_Float16)v;
    return;
  }
  i -= 8192;
  if (i < 8192) out[i] = b_out[0];
}

// ---------------------------------------------------------------------------
// AP/BP: M=8192 atoms, K=256, N=256, fp16 packed output. BM=64 atoms/block,
// 4 waves (one 64-n slice each). blockIdx.y selects AP (with b_in) or BP.
__global__ __launch_bounds__(256) void k_atoms(
    const _Float16* __restrict__ xh,
    const _Float16* __restrict__ wpi, const _Float16* __restrict__ wpj,
    const float* __restrict__ b_in,
    _Float16* __restrict__ AP, _Float16* __restrict__ BP)
{
  const int tid = threadIdx.x;
  const int l = tid & 63, w = tid >> 6;
  const int g = l >> 4, c = l & 15;
  const int which = blockIdx.y;
  const _Float16* wpx = which ? wpj : wpi;
  _Float16* outp = which ? BP : AP;
  const int abase = blockIdx.x * 64;

  f32x4 acc[4][4];
#pragma unroll
  for (int nf = 0; nf < 4; ++nf)
#pragma unroll
    for (int at = 0; at < 4; ++at) acc[nf][at] = (f32x4)0.0f;

#pragma unroll
  for (int ks = 0; ks < 8; ++ks) {
    f16x8 a[4];
#pragma unroll
    for (int nf = 0; nf < 4; ++nf) {
      H8 t; t.u = *(const u32x4*)(wpx + (((w * 4 + nf) * 8 + ks) * 64 + l) * 8);
      a[nf] = t.v;
    }
#pragma unroll
    for (int at = 0; at < 4; ++at) {
      H8 b; b.u = *(const u32x4*)(xh + (abase + at * 16 + c) * 256 + ks * 32 + g * 8);
#pragma unroll
      for (int nf = 0; nf < 4; ++nf)
        acc[nf][at] = MFMA16(a[nf], b.v, acc[nf][at]);
    }
  }

#pragma unroll
  for (int nf = 0; nf < 4; ++nf) {
    const int n = w * 64 + nf * 16 + g * 4;
    f32x4 bias = (f32x4)0.0f;
    if (!which) bias = *(const f32x4*)(b_in + n);
#pragma unroll
    for (int at = 0; at < 4; ++at) {
      const int atom = abase + at * 16 + c;
      const f32x4 t = acc[nf][at] + bias;
      H2 lo, hi;
      lo.h = __builtin_amdgcn_cvt_pkrtz(t[0], t[1]);
      hi.h = __builtin_amdgcn_cvt_pkrtz(t[2], t[3]);
      u32x2 q; q[0] = lo.u; q[1] = hi.u;
      *(u32x2*)(outp + atom * 256 + n) = q;
    }
  }
}

// ---------------------------------------------------------------------------
// Fused edge pipeline. 128 edges/block, 512 threads = 8 waves laid out as
// 2 edge-groups(64) x 4 n-groups(64). h tile [128 edges][256 feat] fp16 in
// LDS. Row swizzle: addr = el*512 + (o ^ sw), sw = (c<<4)|((c&1)<<8).
__global__ __launch_bounds__(512, 4) void k_edges(
    const _Float16* __restrict__ AP, const _Float16* __restrict__ BP,
    const int* __restrict__ idx_i, const int* __restrict__ idx_j,
    const float* __restrict__ d_ij,
    const _Float16* __restrict__ wp, const _Float16* __restrict__ wpr,
    const float* __restrict__ bs, const float* __restrict__ W_out,
    float* __restrict__ out)
{
  __shared__ __align__(16) char hb[65536];
  __shared__ float d_lds[128];
  __shared__ int   ii_lds[128];
  __shared__ int   jj_lds[128];
  __shared__ float oacc[128];

  const int tid = threadIdx.x;
  const int l = tid & 63, w = tid >> 6;
  const int ge = w >> 2, gn = w & 3;
  const int g = l >> 4, c = l & 15;
  const int ebase = blockIdx.x * 128;
  const int we = ge * 64;         // wave's local edge base
  const int nb = gn * 64;         // wave's feature base
  const int sw = (c << 4) | ((c & 1) << 8);  // row swizzle

  if (tid < 128) {
    ii_lds[tid] = idx_i[ebase + tid];
    jj_lds[tid] = idx_j[ebase + tid];
    d_lds[tid]  = d_ij[ebase + tid];
    oacc[tid]   = 0.0f;
  }
  __syncthreads();

  f32x4 acc[4][4];  // [nf][et] : D = h^T tile (features x edges)

  // ---- input layer: rbf(20)+d via one K=32 MFMA step (acc = rbf part) ----
  {
    const float STEP = 15.0f / 19.0f;
    const float C2 = (-0.5f / (STEP * STEP)) * LOG2E;
    f16x8 afr[4];
#pragma unroll
    for (int nf = 0; nf < 4; ++nf) {
      H8 t; t.u = *(const u32x4*)(wpr + ((gn * 4 + nf) * 64 + l) * 8);
      afr[nf] = t.v;
    }
#pragma unroll
    for (int et = 0; et < 4; ++et) {
      const int el = we + et * 16 + c;
      const float d = d_lds[el];
      H8 bb;
#pragma unroll
      for (int j = 0; j < 8; ++j) {
        const int k = g * 8 + j;
        float v = 0.0f;
        if (k < 20)       { const float df = d - (float)k * STEP; v = __builtin_amdgcn_exp2f(C2 * df * df); }
        else if (k == 20) { v = d; }
        bb.h[j] = (_Float16)v;
      }
#pragma unroll
      for (int nf = 0; nf < 4; ++nf)
        acc[nf][et] = (nf == 0 && false) ? acc[nf][et] : MFMA16(afr[nf], bb.v, (et >= 0 ? (f32x4)0.0f : acc[nf][et]));
    }
    // note: acc re-written below properly
#pragma unroll
    for (int et = 0; et < 4; ++et) {
      const int el = we + et * 16 + c;
      const float d = d_lds[el];
      H8 bb;
#pragma unroll
      for (int j = 0; j < 8; ++j) {
        const int k = g * 8 + j;
        float v = 0.0f;
        if (k < 20)       { const float df = d - (float)k * STEP; v = __builtin_amdgcn_exp2f(C2 * df * df); }
        else if (k == 20) { v = d; }
        bb.h[j] = (_Float16)v;
      }
      f32x4 z = (f32x4)0.0f;
#pragma unroll
      for (int nf = 0; nf < 4; ++nf) {
        f32x4 r = MFMA16(afr[nf], bb.v, (nf == 0 ? z : z));
        acc[nf][et] = r;
      }
    }
  }
  // h0 = pack(rbf acc) + AP[idx_i] + BP[idx_j]   (fp16 pk_add), write to LDS
#pragma unroll
  for (int nf = 0; nf < 4; ++nf) {
    const int n = nb + nf * 16 + g * 4;
    const int obase = n * 2;
#pragma unroll
    for (int et = 0; et < 4; ++et) {
      const int el = we + et * 16 + c;
      H4 pa, pb, s;
      pa.u = *(const u32x2*)(AP + ii_lds[el] * 256 + n);
      pb.u = *(const u32x2*)(BP + jj_lds[el] * 256 + n);
      H2 lo, hi;
      lo.h = __builtin_amdgcn_cvt_pkrtz(acc[nf][et][0], acc[nf][et][1]);
      hi.h = __builtin_amdgcn_cvt_pkrtz(acc[nf][et][2], acc[nf][et][3]);
      s.u[0] = lo.u; s.u[1] = hi.u;
      s.v = s.v + pa.v + pb.v;
      *(u32x2*)(hb + el * 512 + (obase ^ sw)) = s.u;
    }
  }
  __syncthreads();

  // one fused hidden-layer matmul: acc = bias + (h_lds @ W)^T
  auto mfma_layer = [&](const _Float16* wl, const float* brow) {
#pragma unroll
    for (int nf = 0; nf < 4; ++nf) {
      const f32x4 bias = *(const f32x4*)(brow + nb + nf * 16 + g * 4);
#pragma unroll
      for (int et = 0; et < 4; ++et) acc[nf][et] = bias;
    }
    __builtin_amdgcn_s_setprio(1);
#pragma unroll
    for (int ks = 0; ks < 8; ++ks) {
      f16x8 a[4];
#pragma unroll
      for (int nf = 0; nf < 4; ++nf) {
        H8 t; t.u = *(const u32x4*)(wl + (((gn * 4 + nf) * 8 + ks) * 64 + l) * 8);
        a[nf] = t.v;
      }
      const int o = (ks * 64 + g * 16) ^ sw;
#pragma unroll
      for (int et = 0; et < 4; ++et) {
        const int el = we + et * 16 + c;
        H8 b; b.u = *(const u32x4*)(hb + el * 512 + o);
#pragma unroll
        for (int nf = 0; nf < 4; ++nf)
          acc[nf][et] = MFMA16(a[nf], b.v, acc[nf][et]);
      }
    }
    __builtin_amdgcn_s_setprio(0);
  };

#pragma unroll 1
  for (int ly = 0; ly < 5; ++ly) {
    mfma_layer(wp + ly * 65536, bs + ly * 256);
    __syncthreads();  // all waves done reading h before in-place overwrite
#pragma unroll
    for (int nf = 0; nf < 4; ++nf) {
      const int n = nb + nf * 16 + g * 4;
      const int obase = n * 2;
#pragma unroll
      for (int et = 0; et < 4; ++et) {
        f32x4 v = acc[nf][et];
#pragma unroll
        for (int j = 0; j < 4; ++j) {
          const float e = __builtin_amdgcn_exp2f(v[j] * -LOG2E);
          v[j] = v[j] * __builtin_amdgcn_rcpf(1.0f + e);   // fast SiLU
        }
        const int el = we + et * 16 + c;
        H2 lo, hi;
        lo.h = __builtin_amdgcn_cvt_pkrtz(v[0], v[1]);
        hi.h = __builtin_amdgcn_cvt_pkrtz(v[2], v[3]);
        u32x2 q; q[0] = lo.u; q[1] = hi.u;
        *(u32x2*)(hb + el * 512 + (obase ^ sw)) = q;
      }
    }
    __syncthreads();
  }

  // layer 6 (no activation): bias already seeded; fold W_out dot immediately
  mfma_layer(wp + 5 * 65536, bs + 5 * 256);
  float sum[4];
#pragma unroll
  for (int et = 0; et < 4; ++et) sum[et] = 0.0f;
#pragma unroll
  for (int nf = 0; nf < 4; ++nf) {
    const int n = nb + nf * 16 + g * 4;
    const f32x4 wo = *(const f32x4*)(W_out + n);
#pragma unroll
    for (int et = 0; et < 4; ++et) {
      const f32x4 v = acc[nf][et];
      sum[et] += v[0] * wo[0] + v[1] * wo[1] + v[2] * wo[2] + v[3] * wo[3];
    }
  }
#pragma unroll
  for (int et = 0; et < 4; ++et) {
    float s = sum[et];
    s += __shfl_xor(s, 16, 64);
    s += __shfl_xor(s, 32, 64);
    if (l < 16) atomicAdd(&oacc[we + et * 16 + l], s);
  }
  __syncthreads();
  if (tid < 128) atomicAdd(out + ii_lds[tid], oacc[tid]);
}

// ---------------------------------------------------------------------------
extern "C" void kernel_launch(void* const* d_in, const int* in_sizes, int n_in,
                              void* d_out, int out_size, void* d_ws, size_t ws_size,
                              hipStream_t stream) {
  (void)in_sizes; (void)n_in; (void)out_size; (void)ws_size;
  const float* x     = (const float*)d_in[0];
  const float* d_ij  = (const float*)d_in[1];
  const int*   idx_i = (const int*)d_in[2];
  const int*   idx_j = (const int*)d_in[3];
  const float* W_in  = (const float*)d_in[4];
  const float* b_in  = (const float*)d_in[5];
  const float* Ws    = (const float*)d_in[6];
  const float* bs    = (const float*)d_in[7];
  const float* W_out = (const float*)d_in[8];
  const float* b_out = (const float*)d_in[9];
  float* out = (float*)d_out;
  char* ws = (char*)d_ws;

  _Float16* wp  = (_Float16*)(ws + WS_WP);
  _Float16* wpi = (_Float16*)(ws + WS_WPI);
  _Float16* wpj = (_Float16*)(ws + WS_WPJ);
  _Float16* wpr = (_Float16*)(ws + WS_WPR);
  _Float16* xh  = (_Float16*)(ws + WS_XH);
  _Float16* AP  = (_Float16*)(ws + WS_AP);
  _Float16* BP  = (_Float16*)(ws + WS_BP);

  hipLaunchKernelGGL(k_prep, dim3(10305), dim3(256), 0, stream,
                     x, W_in, Ws, b_out, wp, wpi, wpj, wpr, xh, out);
  hipLaunchKernelGGL(k_atoms, dim3(128, 2), dim3(256), 0, stream,
                     xh, wpi, wpj, b_in, AP, BP);
  hipLaunchKernelGGL(k_edges, dim3(2048), dim3(512), 0, stream,
                     AP, BP, idx_i, idx_j, d_ij, wp, wpr, bs, W_out, out);
}